// Round 5
// baseline (327.517 us; speedup 1.0000x reference)
//
#include <hip/hip_runtime.h>

// MaskedConv2D bf16-MFMA implicit GEMM, v8. B=8, CIN=COUT=64, H=W=256, K=3, PAD=1.
// GEMM view: M=64 (co), K=576 (ci*9 taps), N=pixels.
//
// v8 vs v7 (post-mortem: LDS permitted 3 blocks/CU but regs didn't:
// 60 arch + 32 acc = 92 -> 5 waves/SIMD -> floor(20/8) = 2 blocks, occ stuck
// at 42%). Fix: split co across waves. Block tile 64co x 4row x 32col; each
// wave owns 32co x 1row x 32col -> acc[2][2] = 16 regs. Total ~76 regs ->
// 6 waves/SIMD under launch_bounds(512,6) with arch cap 69 (>= natural, no
// v6-style spill squeeze). LDS 26112 B. Side wins: per-wave a-loads halve
// (wave reads only its co-half of the weight blob: block L1 weight traffic
// 590KB -> 295KB), MFMA/wave 144->72, staging chunks 7->4. Bias load moved
// to epilogue (saves 8 live regs across the K loop).
//
// mfma_f32_16x16x32_bf16: A[m=lane&15][k=(lane>>4)*8+j], C/D: col=lane&15,
// row=(lane>>4)*4+reg.  Wave w: hrow=w&3, co-half ch=w>>2.

#define B_    8
#define C_    64
#define H_    256
#define W_    256
#define HW_   (H_ * W_)

typedef __attribute__((ext_vector_type(8))) short bf16x8;
typedef __attribute__((ext_vector_type(4))) float f32x4;

__device__ __forceinline__ unsigned short f2bf(float f) {
    unsigned int u = __float_as_uint(f);
    u = (u + 0x7FFFu + ((u >> 16) & 1u)) >> 16;   // RNE
    return (unsigned short)u;
}

// ---- weight conversion: fp32 [co][ci][3][3] -> bf16 A-fragment blob ----
// frag f = s*4 + mf  (s = tap*2 + kblk); lane l holds 8 bf16 at (f*64+l)*16 B:
//   co = mf*16 + (l&15); ci = kblk*32 + (l>>4)*8 + j
__global__ __launch_bounds__(256) void wconv(const float* __restrict__ wgt,
                                             unsigned short* __restrict__ wsA)
{
    const int gid  = blockIdx.x * 256 + threadIdx.x;   // 18*256 = 4608
    const int s    = gid >> 8;
    const int rest = gid & 255;
    const int mf   = rest >> 6;
    const int lane = rest & 63;
    const int tap  = s >> 1;
    const int kblk = s & 1;
    const int kh = tap / 3, kw = tap % 3;
    const int co = mf * 16 + (lane & 15);
    unsigned short v[8];
#pragma unroll
    for (int j = 0; j < 8; ++j) {
        const int ci = kblk * 32 + (lane >> 4) * 8 + j;
        v[j] = f2bf(wgt[((co * C_ + ci) * 3 + kh) * 3 + kw]);
    }
    unsigned short* dst = wsA + (size_t)gid * 8;
    *(uint4*)dst = *(const uint4*)v;
}

// ---- main kernel ----
#define TROWS 6          // 4 + 2 halo
#define TCOLS 34         // 32 + 2 halo
#define NU    (TROWS * TCOLS * 8)   // 1632 staging units
#define NCHUNK 4                    // ceil(1632/512)
#define NTAIL (NU - 3 * 512)        // 96

__global__ __launch_bounds__(512, 6) void masked_conv_mfma(
    const float* __restrict__ x,
    const float* __restrict__ mask,
    const unsigned short* __restrict__ wsA,
    const float* __restrict__ bias,
    float* __restrict__ out)
{
    // [cell = row*34+col][8 ci-octets, XOR-swizzled], 16B units. 26112 B.
    __shared__ __align__(16) unsigned short xs[TROWS * TCOLS * 64];

    const int tid  = threadIdx.x;
    const int wave = tid >> 6;
    const int lane = tid & 63;
    const int l15  = lane & 15;
    const int lq   = lane >> 4;

    const int w0 = blockIdx.x * 32;
    const int h0 = blockIdx.y * 4;
    const int b  = blockIdx.z;

    const float* xb = x + (size_t)b * C_ * HW_;

    const int hrow = wave & 3;        // output row within tile
    const int ch   = wave >> 2;       // co half (0/1)
    const int h    = h0 + hrow;
    const int pcol = w0 + (lane & 31);

    // ---- validity: branchless, loads issue early (overlap staging). Lanes
    // 0..31 cover the wave's 32 px (lanes 32..63 duplicate).
    int valid = 0;
    {
        const float* mb = mask + (size_t)b * HW_;
#pragma unroll
        for (int dh = -1; dh <= 1; ++dh) {
#pragma unroll
            for (int dw = -1; dw <= 1; ++dw) {
                const int hh = h + dh;
                const int ww = pcol + dw;
                const int ok = (hh >= 0) & (hh < H_) & (ww >= 0) & (ww < W_);
                const float mv = mb[ok ? (hh * W_ + ww) : 0];
                valid |= ok & (mv != 0.0f ? 1 : 0);
            }
        }
    }

    // ---- stage x tile: [6 rows][34 cols][64 ci] bf16 ----
    // Work unit = (row, ci-octet, col): 8 strided global dwords -> 1 ds_write_b128.
    // Phase A: issue loads with branchless clamped addresses so they pipeline.
    float va[NCHUNK][8];
    int   cell[NCHUNK];
    int   okf[NCHUNK];
#pragma unroll
    for (int k = 0; k < NCHUNK; ++k) {
        const int u0 = tid + (k << 9);
        const int u  = (u0 < NU) ? u0 : 0;        // clamp: dup unit 0, write guarded
        const int col = u % TCOLS;
        const int t2  = u / TCOLS;
        const int oct = t2 & 7;
        const int row = t2 >> 3;
        const int gh = h0 - 1 + row;
        const int gw = w0 - 1 + col;
        const int ok = (gh >= 0) & (gh < H_) & (gw >= 0) & (gw < W_);
        const float* px = xb + ((size_t)(oct * 8) * H_ + (ok ? gh : 0)) * W_
                             + (ok ? gw : 0);
#pragma unroll
        for (int j = 0; j < 8; ++j) va[k][j] = px[(size_t)j * HW_];
        const int c = row * TCOLS + col;
        cell[k] = (c << 6) + ((oct ^ (c & 7)) << 3);   // XOR-swizzled octet slot
        okf[k]  = ok;
    }
    // Phase B: convert + LDS write
#pragma unroll
    for (int k = 0; k < NCHUNK; ++k) {
        if (k == NCHUNK - 1 && tid >= NTAIL) continue;
        unsigned short v[8];
#pragma unroll
        for (int j = 0; j < 8; ++j)
            v[j] = okf[k] ? f2bf(va[k][j]) : (unsigned short)0;
        *(uint4*)&xs[cell[k]] = *(const uint4*)v;
    }

    __syncthreads();

    // ---- validity bpermutes (2 regs kept live; bias deferred to epilogue) ----
    const int vn0 = __builtin_amdgcn_ds_bpermute(l15 << 2, valid);
    const int vn1 = __builtin_amdgcn_ds_bpermute((16 + l15) << 2, valid);

    // ---- K loop: 9 taps x 2 ci-halves, no barriers ----
    f32x4 acc[2][2];
#pragma unroll
    for (int mf = 0; mf < 2; ++mf)
#pragma unroll
        for (int nf = 0; nf < 2; ++nf)
            acc[mf][nf] = (f32x4){0.f, 0.f, 0.f, 0.f};

    const bf16x8* wA = (const bf16x8*)wsA;

#pragma unroll 1
    for (int kh = 0; kh < 3; ++kh) {
        const int rowbase = (hrow + kh) * TCOLS;
#pragma unroll
        for (int kw = 0; kw < 3; ++kw) {
#pragma unroll
            for (int kblk = 0; kblk < 2; ++kblk) {
                const int s = (kh * 3 + kw) * 2 + kblk;
                bf16x8 a[2];
#pragma unroll
                for (int mf = 0; mf < 2; ++mf)
                    a[mf] = wA[(s * 4 + ch * 2 + mf) * 64 + lane];
                bf16x8 bfv[2];
#pragma unroll
                for (int nf = 0; nf < 2; ++nf) {
                    const int cell2 = rowbase + nf * 16 + l15 + kw;
                    const int g = kblk * 4 + lq;               // ci-octet group
                    bfv[nf] = *(const bf16x8*)
                        &xs[(cell2 << 6) + ((g ^ (cell2 & 7)) << 3)];
                }
#pragma unroll
                for (int mf = 0; mf < 2; ++mf)
#pragma unroll
                    for (int nf = 0; nf < 2; ++nf)
                        acc[mf][nf] = __builtin_amdgcn_mfma_f32_16x16x32_bf16(
                            a[mf], bfv[nf], acc[mf][nf], 0, 0, 0);
            }
        }
    }

    // ---- epilogue: bias (L1-hot) + mask select + store ----
#pragma unroll
    for (int nf = 0; nf < 2; ++nf) {
        const int cloc = nf * 16 + l15;                       // 0..31 within tile
        const int vn = nf ? vn1 : vn0;
        float* ob = out + ((size_t)(b * C_) * H_ + h) * W_ + w0 + cloc;
#pragma unroll
        for (int mf = 0; mf < 2; ++mf) {
#pragma unroll
            for (int reg = 0; reg < 4; ++reg) {
                const int co = ch * 32 + mf * 16 + lq * 4 + reg;
                const float val = vn ? (acc[mf][nf][reg] + bias[co]) : 0.0f;
                ob[(size_t)co * HW_] = val;
            }
        }
    }
}

extern "C" void kernel_launch(void* const* d_in, const int* in_sizes, int n_in,
                              void* d_out, int out_size, void* d_ws, size_t ws_size,
                              hipStream_t stream) {
    const float* x    = (const float*)d_in[0];
    const float* mask = (const float*)d_in[1];
    const float* wgt  = (const float*)d_in[2];
    const float* bias = (const float*)d_in[3];
    float* out        = (float*)d_out;
    unsigned short* wsA = (unsigned short*)d_ws;   // 73728 B used

    wconv<<<18, 256, 0, stream>>>(wgt, wsA);

    dim3 grid(W_ / 32, H_ / 4, B_);
    masked_conv_mfma<<<grid, 512, 0, stream>>>(x, mask, wsA, bias, out);
}